// Round 5
// baseline (475.173 us; speedup 1.0000x reference)
//
#include <hip/hip_runtime.h>
#include <hip/hip_bf16.h>
#include <math.h>

typedef __bf16 bf16;
typedef __bf16 bf16x4 __attribute__((ext_vector_type(4)));
typedef __bf16 bf16x8 __attribute__((ext_vector_type(8)));
typedef short shortx4 __attribute__((ext_vector_type(4)));
typedef float floatx4 __attribute__((ext_vector_type(4)));

#define LOG2E 1.44269504088896340736f
#define QSCALE 0.18033688011112042f  /* 0.125 * log2(e), folded into Q store */
#define AS1 __attribute__((address_space(1)))
#define AS3 __attribute__((address_space(3)))

__device__ __forceinline__ void async_g2l16(const bf16* g, bf16* l) {
  __builtin_amdgcn_global_load_lds((AS1 void*)(void*)g, (AS3 void*)(void*)l, 16, 0, 0);
}
__device__ __forceinline__ shortx4 as_s4(bf16x4 v) {
  shortx4 r;
  __builtin_memcpy(&r, &v, 8);
  return r;
}

// -------- fused: 7 weight transposes (z<7) + embedding (z==7) --------
struct TransArgs {
  const float* src[7];
  bf16* dst[7];
  int cblk[7];  // C/64
  const int* data;
  const float* emb;
  bf16* eout;
};
__global__ __launch_bounds__(256) void prep_kernel(TransArgs a) {
  int z = blockIdx.z;
  int t = threadIdx.x;
  if (z == 7) {  // embedding + sinusoidal pos: 512 blocks x 8 rows
    int idx = blockIdx.y * 32 + blockIdx.x;
#pragma unroll
    for (int r8 = 0; r8 < 8; r8++) {
      int row = idx * 8 + r8;  // b*1024 + s
      int s = row & 1023;
      int tok = a.data[row];
      int d = t * 4;
      floatx4 ev = *(const floatx4*)(a.emb + (size_t)tok * 1024 + d);
      bf16x4 ov;
#pragma unroll
      for (int pr = 0; pr < 2; pr++) {
        int di = d + pr * 2;
        float freq = exp2f(-(float)di * (13.287712379549449f / 1024.0f));
        float ang = (float)s * freq;
        float sv, cv;
        __sincosf(ang, &sv, &cv);
        ov[pr * 2] = (bf16)(ev[pr * 2] * 32.0f + sv);
        ov[pr * 2 + 1] = (bf16)(ev[pr * 2 + 1] * 32.0f + cv);
      }
      *(bf16x4*)(a.eout + (size_t)row * 1024 + d) = ov;
    }
    return;
  }
  if ((int)blockIdx.x >= a.cblk[z]) return;
  const float* __restrict__ src = a.src[z];
  bf16* __restrict__ dst = a.dst[z];
  int C = a.cblk[z] * 64;
  __shared__ __align__(16) bf16 tile[64][72];
  int c0 = blockIdx.x * 64, r0 = blockIdx.y * 64;
  int r = t >> 2, cg = (t & 3) * 16;
  const float* sp = src + (size_t)(r0 + r) * C + c0 + cg;
  floatx4 f0 = *(const floatx4*)sp;
  floatx4 f1 = *(const floatx4*)(sp + 4);
  floatx4 f2 = *(const floatx4*)(sp + 8);
  floatx4 f3 = *(const floatx4*)(sp + 12);
  bf16x8 v0, v1;
#pragma unroll
  for (int i = 0; i < 4; i++) {
    v0[i] = (bf16)f0[i];
    v0[4 + i] = (bf16)f1[i];
    v1[i] = (bf16)f2[i];
    v1[4 + i] = (bf16)f3[i];
  }
  *(bf16x8*)&tile[r][cg] = v0;
  *(bf16x8*)&tile[r][cg + 8] = v1;
  __syncthreads();
  bf16x8 o0, o1;
#pragma unroll
  for (int i = 0; i < 8; i++) o0[i] = tile[cg + i][r];
#pragma unroll
  for (int i = 0; i < 8; i++) o1[i] = tile[cg + 8 + i][r];
  bf16* dp = dst + (size_t)(c0 + r) * 1024 + r0 + cg;
  *(bf16x8*)dp = o0;
  *(bf16x8*)(dp + 8) = o1;
}

// ---------------- GEMM (m97-style, unchanged structure) ----------------
// EPI=0: C0[m][n] stride N. EPI=1 (QKV): n<1024 -> Q (pre-scaled by QSCALE),
// n<2048 -> K, else -> Vt transposed store.
template <int EPI, int MT>
__global__ __launch_bounds__(256, 3) void gemm_kernel(const bf16* __restrict__ A,
                                                      const bf16* __restrict__ Bt,
                                                      bf16* __restrict__ C0,
                                                      bf16* __restrict__ C1,
                                                      bf16* __restrict__ Vt, int N) {
  constexpr int NJ = (MT == 128) ? 4 : 2;
  constexpr int PA = MT / 32;
  __shared__ __align__(16) bf16 As[MT * 64];
  __shared__ __align__(16) bf16 Bs[128 * 64];
  const int K = 1024;
  int m0 = blockIdx.x * MT, n0 = blockIdx.y * 128;
  int t = threadIdx.x;
  int l = t & 63, w = t >> 6;
  int lr = l & 15, qd = l >> 4;
  int xorb = lr & 7;
  int wrow = __builtin_amdgcn_readfirstlane(t & 192);
  int wm = (MT == 128) ? (w & 1) : 0;
  int wn = (MT == 128) ? (w >> 1) : w;
  int mwbase = wm * 64;
  int nwbase = (MT == 128) ? (wn * 64) : (wn * 32);
  floatx4 acc[4][NJ] = {};
  for (int k0 = 0; k0 < K; k0 += 64) {
#pragma unroll
    for (int p = 0; p < PA; p++) {
      int jl = p * 256 + t;
      int r = jl >> 3;
      int bi = (jl & 7) ^ (r & 7);
      async_g2l16(A + (size_t)(m0 + r) * K + k0 + bi * 8, &As[(p * 256 + wrow) * 8]);
    }
#pragma unroll
    for (int p = 0; p < 4; p++) {
      int jl = p * 256 + t;
      int r = jl >> 3;
      int bi = (jl & 7) ^ (r & 7);
      async_g2l16(Bt + (size_t)(n0 + r) * K + k0 + bi * 8, &Bs[(p * 256 + wrow) * 8]);
    }
    __syncthreads();
#pragma unroll
    for (int c = 0; c < 2; c++) {
      bf16x8 fa[4], fb[NJ];
#pragma unroll
      for (int i = 0; i < 4; i++)
        fa[i] = *(const bf16x8*)&As[(mwbase + i * 16 + lr) * 64 + ((c * 4 + qd) ^ xorb) * 8];
#pragma unroll
      for (int j = 0; j < NJ; j++)
        fb[j] = *(const bf16x8*)&Bs[(nwbase + j * 16 + lr) * 64 + ((c * 4 + qd) ^ xorb) * 8];
#pragma unroll
      for (int i = 0; i < 4; i++)
#pragma unroll
        for (int j = 0; j < NJ; j++)
          acc[i][j] = __builtin_amdgcn_mfma_f32_16x16x32_bf16(fa[i], fb[j], acc[i][j], 0, 0, 0);
    }
    __syncthreads();
  }
#pragma unroll
  for (int i = 0; i < 4; i++) {
    int mbase = m0 + mwbase + i * 16 + qd * 4;
#pragma unroll
    for (int j = 0; j < NJ; j++) {
      int n = n0 + nwbase + j * 16 + lr;
      if (EPI == 0) {
#pragma unroll
        for (int r = 0; r < 4; r++)
          C0[(size_t)(mbase + r) * N + n] = (bf16)acc[i][j][r];
      } else {
        if (n < 1024) {
#pragma unroll
          for (int r = 0; r < 4; r++)
            C0[(size_t)(mbase + r) * 1024 + n] = (bf16)(acc[i][j][r] * QSCALE);
        } else if (n < 2048) {
#pragma unroll
          for (int r = 0; r < 4; r++)
            C1[(size_t)(mbase + r) * 1024 + (n - 1024)] = (bf16)acc[i][j][r];
        } else {
          int nn = n - 2048;
          int h = nn >> 6, d = nn & 63;
          int bb = mbase >> 10, s = mbase & 1023;
          bf16x4 v = {(bf16)acc[i][j][0], (bf16)acc[i][j][1],
                      (bf16)acc[i][j][2], (bf16)acc[i][j][3]};
          *(bf16x4*)(Vt + ((size_t)((bb * 16 + h) * 64 + d) << 10) + s) = v;
        }
      }
    }
  }
}

// ------- barrier-free key-split flash attention: 256 thr, Br=64 q, waves split keys -------
// Scores computed TRANSPOSED: Sc^T[key][q] = mfma32(Kfrag, Qfrag). Its C-layout
// (col=lane&15=q, row=(lane>>4)*4+reg=key) is exactly the B-operand layout of
// mfma_16x16x16 (n=lane&15, k=(lane>>4)*4+j) -> exp(sc) feeds PV directly from
// registers. No LDS / no __syncthreads in the K-loop; one barrier for the final
// cross-wave O/lsum reduction. Q pre-scaled by QSCALE at projection.
__global__ __launch_bounds__(256) void attn_kernel(const bf16* __restrict__ Q,
                                                   const bf16* __restrict__ Kb,
                                                   const bf16* __restrict__ Vt,
                                                   bf16* __restrict__ O,
                                                   int Skv, int memmode) {
  __shared__ __align__(16) float Ored[3][64][68];
  __shared__ float Lred[3][64];
  int bid = blockIdx.x;  // 16 qb x 16 h x 4 b
  int qb = bid & 15, h = (bid >> 4) & 15, b = bid >> 8;
  int t = threadIdx.x, w = t >> 6, l = t & 63;
  int lr = l & 15, qd = l >> 4;
  int q0 = qb * 64;
  // Q B-fragments, block-resident: q = qg*16+lr, dims qd*8.. (+32)
  bf16x8 aq[4][2];
#pragma unroll
  for (int qg = 0; qg < 4; qg++) {
    const bf16* Qrow = Q + (size_t)(b * 1024 + q0 + qg * 16 + lr) * 1024 + h * 64;
    aq[qg][0] = *(const bf16x8*)(Qrow + qd * 8);
    aq[qg][1] = *(const bf16x8*)(Qrow + 32 + qd * 8);
  }
  floatx4 Oacc[4][4] = {};            // [dd][qg]: d=dd*16+qd*4+r, q=qg*16+lr
  float lsum[4] = {0.f, 0.f, 0.f, 0.f};
  const bf16* Kbase = Kb + (size_t)b * 1024 * 1024 + h * 64;
  const bf16* Vbase = Vt + (size_t)(b * 16 + h) * 64 * 1024;
  int nkt = (Skv + 63) >> 6;
  for (int kt = 0; kt < nkt; kt++) {
    int j0 = kt * 64;
    // K A-fragment: this wave's 16 keys, m=lr
    int key = j0 + w * 16 + lr;
    int kc = min(key, Skv - 1);
    int tok = memmode ? (kc < 16 ? 1008 + kc : kc - 16) : kc;
    const bf16* kp = Kbase + (size_t)tok * 1024 + qd * 8;
    bf16x8 ka0 = *(const bf16x8*)kp;
    bf16x8 ka1 = *(const bf16x8*)(kp + 32);
    // V^T A-fragments: m=d=dd*16+lr, k=key qd*4+j (4 contiguous tokens)
    int jb = j0 + w * 16 + qd * 4;
    int jc = min(jb, Skv - 4);
    int tv = memmode ? (jc < 16 ? 1008 + jc : jc - 16) : jc;
    bf16x4 va[4];
#pragma unroll
    for (int dd = 0; dd < 4; dd++)
      va[dd] = *(const bf16x4*)(Vbase + (size_t)(dd * 16 + lr) * 1024 + tv);
    // Sc^T = K . Q^T
    floatx4 sc[4] = {};
#pragma unroll
    for (int qg = 0; qg < 4; qg++) {
      sc[qg] = __builtin_amdgcn_mfma_f32_16x16x32_bf16(ka0, aq[qg][0], sc[qg], 0, 0, 0);
      sc[qg] = __builtin_amdgcn_mfma_f32_16x16x32_bf16(ka1, aq[qg][1], sc[qg], 0, 0, 0);
    }
    // p = exp2(sc) (Q pre-scaled); mask tail keys; feed PV directly
    shortx4 ps[4];
#pragma unroll
    for (int qg = 0; qg < 4; qg++) {
      bf16x4 pt;
#pragma unroll
      for (int r = 0; r < 4; r++) {
        int kkey = j0 + w * 16 + qd * 4 + r;
        float p = exp2f(sc[qg][r]);
        p = (kkey < Skv) ? p : 0.0f;
        lsum[qg] += p;
        pt[r] = (bf16)p;
      }
      ps[qg] = as_s4(pt);
    }
#pragma unroll
    for (int dd = 0; dd < 4; dd++) {
      shortx4 vs = as_s4(va[dd]);
#pragma unroll
      for (int qg = 0; qg < 4; qg++)
        Oacc[dd][qg] =
            __builtin_amdgcn_mfma_f32_16x16x16bf16_1k(vs, ps[qg], Oacc[dd][qg], 0, 0, 0);
    }
  }
  // reduce lsum over qd groups within wave
#pragma unroll
  for (int qg = 0; qg < 4; qg++) {
    lsum[qg] += __shfl_xor(lsum[qg], 16);
    lsum[qg] += __shfl_xor(lsum[qg], 32);
  }
  // park waves 1..3, single barrier, wave 0 combines + stores
  if (w > 0) {
#pragma unroll
    for (int dd = 0; dd < 4; dd++)
#pragma unroll
      for (int qg = 0; qg < 4; qg++)
        *(floatx4*)&Ored[w - 1][qg * 16 + lr][dd * 16 + qd * 4] = Oacc[dd][qg];
    if (qd == 0) {
#pragma unroll
      for (int qg = 0; qg < 4; qg++) Lred[w - 1][qg * 16 + lr] = lsum[qg];
    }
  }
  __syncthreads();
  if (w == 0) {
    float linv[4];
#pragma unroll
    for (int qg = 0; qg < 4; qg++) {
      float s = lsum[qg] + Lred[0][qg * 16 + lr] + Lred[1][qg * 16 + lr] +
                Lred[2][qg * 16 + lr];
      linv[qg] = 1.0f / s;
    }
#pragma unroll
    for (int dd = 0; dd < 4; dd++)
#pragma unroll
      for (int qg = 0; qg < 4; qg++) {
        floatx4 o = Oacc[dd][qg];
#pragma unroll
        for (int v = 0; v < 3; v++)
          o += *(const floatx4*)&Ored[v][qg * 16 + lr][dd * 16 + qd * 4];
        bf16x4 ob;
#pragma unroll
        for (int r = 0; r < 4; r++) ob[r] = (bf16)(o[r] * linv[qg]);
        *(bf16x4*)(O + (size_t)(b * 1024 + q0 + qg * 16 + lr) * 1024 + h * 64 +
                   dd * 16 + qd * 4) = ob;
      }
  }
}

// ---------------- layernorm: out = LN(x + res) * g + b ----------------
template <typename OutT>
__global__ __launch_bounds__(256) void ln_kernel(const bf16* __restrict__ x,
                                                 const bf16* __restrict__ res,
                                                 const float* __restrict__ g,
                                                 const float* __restrict__ bta,
                                                 OutT* __restrict__ out) {
  __shared__ float red1[4], red2[4];
  int row = blockIdx.x, t = threadIdx.x;
  size_t base = (size_t)row * 1024 + t * 4;
  bf16x4 xv = *(const bf16x4*)(x + base);
  bf16x4 rv = *(const bf16x4*)(res + base);
  float v[4];
  float s = 0.f;
#pragma unroll
  for (int i = 0; i < 4; i++) {
    v[i] = (float)xv[i] + (float)rv[i];
    s += v[i];
  }
#pragma unroll
  for (int m = 32; m; m >>= 1) s += __shfl_xor(s, m);
  if ((t & 63) == 0) red1[t >> 6] = s;
  __syncthreads();
  float mu = (red1[0] + red1[1] + red1[2] + red1[3]) * (1.0f / 1024.0f);
  float sq = 0.f;
#pragma unroll
  for (int i = 0; i < 4; i++) {
    float dd = v[i] - mu;
    sq += dd * dd;
  }
#pragma unroll
  for (int m = 32; m; m >>= 1) sq += __shfl_xor(sq, m);
  if ((t & 63) == 0) red2[t >> 6] = sq;
  __syncthreads();
  float var = (red2[0] + red2[1] + red2[2] + red2[3]) * (1.0f / 1024.0f);
  float rs = rsqrtf(var + 1e-5f);
  floatx4 gv = *(const floatx4*)(g + t * 4);
  floatx4 bv = *(const floatx4*)(bta + t * 4);
  if constexpr (sizeof(OutT) == 2) {
    bf16x4 ov;
#pragma unroll
    for (int i = 0; i < 4; i++)
      ov[i] = (bf16)((v[i] - mu) * rs * gv[i] + bv[i]);
    *(bf16x4*)(out + base) = ov;
  } else {
    floatx4 ov;
#pragma unroll
    for (int i = 0; i < 4; i++)
      ov[i] = (v[i] - mu) * rs * gv[i] + bv[i];
    *(floatx4*)(out + base) = ov;
  }
}

// ------- fused stage-2 double layernorm + new_mem emit -------
__global__ __launch_bounds__(256) void dualln_kernel(const bf16* __restrict__ x,
                                                     const bf16* __restrict__ hids,
                                                     const float* __restrict__ g1,
                                                     const float* __restrict__ b1,
                                                     const float* __restrict__ g2,
                                                     const float* __restrict__ b2,
                                                     bf16* __restrict__ out,
                                                     float* __restrict__ newmem) {
  __shared__ float ra[4], rb[4], rc[4], rd[4];
  int row = blockIdx.x, t = threadIdx.x;
  size_t base = (size_t)row * 1024 + t * 4;
  bf16x4 xv = *(const bf16x4*)(x + base);
  bf16x4 hv = *(const bf16x4*)(hids + base);
  float hf[4], v[4];
  float s = 0.f;
#pragma unroll
  for (int i = 0; i < 4; i++) {
    hf[i] = (float)hv[i];
    v[i] = (float)xv[i] + hf[i];
    s += v[i];
  }
  int ss = row & 1023;
  if (ss >= 1008) {
    int bb = row >> 10;
    floatx4 mv = {hf[0], hf[1], hf[2], hf[3]};
    *(floatx4*)(newmem + ((size_t)(bb * 16 + ss - 1008) << 10) + t * 4) = mv;
  }
#pragma unroll
  for (int m = 32; m; m >>= 1) s += __shfl_xor(s, m);
  if ((t & 63) == 0) ra[t >> 6] = s;
  __syncthreads();
  float mu = (ra[0] + ra[1] + ra[2] + ra[3]) * (1.0f / 1024.0f);
  float sq = 0.f;
#pragma unroll
  for (int i = 0; i < 4; i++) {
    float dd = v[i] - mu;
    sq += dd * dd;
  }
#pragma unroll
  for (int m = 32; m; m >>= 1) sq += __shfl_xor(sq, m);
  if ((t & 63) == 0) rb[t >> 6] = sq;
  __syncthreads();
  float var = (rb[0] + rb[1] + rb[2] + rb[3]) * (1.0f / 1024.0f);
  float rs = rsqrtf(var + 1e-5f);
  floatx4 g1v = *(const floatx4*)(g1 + t * 4);
  floatx4 b1v = *(const floatx4*)(b1 + t * 4);
  float y[4];
  float s2 = 0.f;
#pragma unroll
  for (int i = 0; i < 4; i++) {
    float a = (v[i] - mu) * rs * g1v[i] + b1v[i];
    y[i] = hf[i] + a;
    s2 += y[i];
  }
#pragma unroll
  for (int m = 32; m; m >>= 1) s2 += __shfl_xor(s2, m);
  if ((t & 63) == 0) rc[t >> 6] = s2;
  __syncthreads();
  float mu2 = (rc[0] + rc[1] + rc[2] + rc[3]) * (1.0f / 1024.0f);
  float sq2 = 0.f;
#pragma unroll
  for (int i = 0; i < 4; i++) {
    float dd = y[i] - mu2;
    sq2 += dd * dd;
  }
#pragma unroll
  for (int m = 32; m; m >>= 1) sq2 += __shfl_xor(sq2, m);
  if ((t & 63) == 0) rd[t >> 6] = sq2;
  __syncthreads();
  float var2 = (rd[0] + rd[1] + rd[2] + rd[3]) * (1.0f / 1024.0f);
  float rs2 = rsqrtf(var2 + 1e-5f);
  floatx4 g2v = *(const floatx4*)(g2 + t * 4);
  floatx4 b2v = *(const floatx4*)(b2 + t * 4);
  bf16x4 ov;
#pragma unroll
  for (int i = 0; i < 4; i++)
    ov[i] = (bf16)((y[i] - mu2) * rs2 * g2v[i] + b2v[i]);
  *(bf16x4*)(out + base) = ov;
}

extern "C" void kernel_launch(void* const* d_in, const int* in_sizes, int n_in,
                              void* d_out, int out_size, void* d_ws, size_t ws_size,
                              hipStream_t stream) {
  const int* data = (const int*)d_in[0];
  const float* emb = (const float*)d_in[2];
  const float* a_qw = (const float*)d_in[3];
  const float* a_kvw = (const float*)d_in[4];
  const float* a_ow = (const float*)d_in[5];
  const float* a_g = (const float*)d_in[6];
  const float* a_b = (const float*)d_in[7];
  const float* o_qw = (const float*)d_in[16];
  const float* o_kvw = (const float*)d_in[17];
  const float* o_ow = (const float*)d_in[18];
  const float* o_g = (const float*)d_in[19];
  const float* o_b = (const float*)d_in[20];
  const float* ff2_w = (const float*)d_in[21];
  const float* ln1_g = (const float*)d_in[22];
  const float* ln1_b = (const float*)d_in[23];
  const float* ln2_g = (const float*)d_in[24];
  const float* ln2_b = (const float*)d_in[25];
  float* out = (float*)d_out;

  char* ws = (char*)d_ws;
  size_t off = 0;
  auto alloc = [&](size_t elems) {
    bf16* p = (bf16*)(ws + off);
    off += elems * 2;
    return p;
  };
  bf16* Wt_s1 = alloc(3072 * 1024);
  bf16* Wt_s2 = alloc(3072 * 1024);
  bf16* Wt_aow = alloc(1024 * 1024);
  bf16* Wt_oow = alloc(1024 * 1024);
  bf16* Wt_ff2 = alloc(1024 * 1024);
  bf16* hids0 = alloc(4096 * 1024);
  bf16* hids = alloc(4096 * 1024);
  bf16* Qb = alloc(4096 * 1024);
  bf16* Kb = alloc(4096 * 1024);
  bf16* Vtb = alloc(4096 * 1024);
  bf16* vecb = alloc(4096 * 1024);
  bf16* projb = Qb;

  dim3 tb(256);
  TransArgs ta;
  ta.src[0] = a_qw;  ta.dst[0] = Wt_s1;               ta.cblk[0] = 16;
  ta.src[1] = a_kvw; ta.dst[1] = Wt_s1 + 1024 * 1024; ta.cblk[1] = 32;
  ta.src[2] = o_qw;  ta.dst[2] = Wt_s2;               ta.cblk[2] = 16;
  ta.src[3] = o_kvw; ta.dst[3] = Wt_s2 + 1024 * 1024; ta.cblk[3] = 32;
  ta.src[4] = a_ow;  ta.dst[4] = Wt_aow;              ta.cblk[4] = 16;
  ta.src[5] = o_ow;  ta.dst[5] = Wt_oow;              ta.cblk[5] = 16;
  ta.src[6] = ff2_w; ta.dst[6] = Wt_ff2;              ta.cblk[6] = 16;
  ta.data = data;
  ta.emb = emb;
  ta.eout = hids0;
  prep_kernel<<<dim3(32, 16, 8), tb, 0, stream>>>(ta);

  // stage 1
  gemm_kernel<1, 128><<<dim3(32, 24), tb, 0, stream>>>(hids0, Wt_s1, Qb, Kb, Vtb, 3072);
  attn_kernel<<<1024, tb, 0, stream>>>(Qb, Kb, Vtb, vecb, 1024, 0);
  gemm_kernel<0, 64><<<dim3(64, 8), tb, 0, stream>>>(vecb, Wt_aow, projb, nullptr, nullptr, 1024);
  ln_kernel<bf16><<<4096, tb, 0, stream>>>(projb, hids0, a_g, a_b, hids);

  // stage 2 (new_mem = hids rows 1008..1023)
  gemm_kernel<1, 128><<<dim3(32, 24), tb, 0, stream>>>(hids, Wt_s2, Qb, Kb, Vtb, 3072);
  attn_kernel<<<1024, tb, 0, stream>>>(Qb, Kb, Vtb, vecb, 1040, 1);
  gemm_kernel<0, 64><<<dim3(64, 8), tb, 0, stream>>>(vecb, Wt_oow, projb, nullptr, nullptr, 1024);
  dualln_kernel<<<4096, tb, 0, stream>>>(projb, hids, o_g, o_b, ln1_g, ln1_b, hids0,
                                         out + 4194304);

  // final ff + LN -> d_out (fp32)
  gemm_kernel<0, 64><<<dim3(64, 8), tb, 0, stream>>>(hids0, Wt_ff2, projb, nullptr, nullptr, 1024);
  ln_kernel<float><<<4096, tb, 0, stream>>>(projb, hids0, ln2_g, ln2_b, out);
}